// Round 10
// baseline (224.324 us; speedup 1.0000x reference)
//
#include <hip/hip_runtime.h>
#include <hip/hip_bf16.h>

#define B_ 2
#define L_ 256
#define T_ 250
#define D_ 1024
#define NH_ 16
#define DH_ 64
#define CRv_ 16
#define HID_ 64
#define CL_ 16
#define OUT_ 1024
#define MEMROWS_ 64001L
#define TCH_ 25
#define NTCH_ (T_ / TCH_)   // 10

#define AS1 __attribute__((address_space(1)))
#define AS3 __attribute__((address_space(3)))

typedef __attribute__((ext_vector_type(2))) _Float16 h16x2;
typedef __attribute__((ext_vector_type(8))) _Float16 h16x8;
typedef __attribute__((ext_vector_type(4))) float f32x4;

__device__ __forceinline__ h16x2 cvt_pk(float lo, float hi) {
    return __builtin_bit_cast(h16x2, __builtin_amdgcn_cvt_pkrtz(lo, hi));
}

struct H4 { h16x2 a, b, c, d; };
__device__ __forceinline__ h16x8 packH4(h16x2 a, h16x2 b, h16x2 c, h16x2 d) {
    H4 h{a, b, c, d};
    return __builtin_bit_cast(h16x8, h);
}
__device__ __forceinline__ h16x2 hsplat(float x) {
    _Float16 h = (_Float16)x;
    h16x2 v; v[0] = h; v[1] = h;
    return v;
}
__device__ __forceinline__ unsigned pkadd(unsigned a, unsigned b) {
    h16x2 r = __builtin_bit_cast(h16x2, a) + __builtin_bit_cast(h16x2, b);
    return __builtin_bit_cast(unsigned, r);
}

// Packed-f16 gelu * w2 accumulate, PRE-HALVED input: aH = x/2 (W1,b1 pre-scaled by 0.5).
// E(t)=t*P~(t^2), t=clamp(aH,+-1.75) ~ erf(x/sqrt2); gelu = aH*E + aH. 10 pk-ops.
__device__ __forceinline__ void gelu_w2_pk(h16x2 aH, h16x2 w, h16x2& pacc) {
    const h16x2 C0 = hsplat(1.5957600f);
    const h16x2 C1 = hsplat(-1.0445624f);
    const h16x2 C2 = hsplat(0.5417632f);
    const h16x2 C3 = hsplat(-0.15817472f);
    const h16x2 C4 = hsplat(0.018604288f);
    h16x2 t  = __builtin_elementwise_min(__builtin_elementwise_max(aH, hsplat(-1.75f)), hsplat(1.75f));
    h16x2 s  = t * t;
    h16x2 p  = C4 * s + C3;
    p = p * s + C2;
    p = p * s + C1;
    p = p * s + C0;
    h16x2 e  = t * p;
    h16x2 g  = aH * e + aH;
    pacc = g * w + pacc;
}

#define WAITV(n) asm volatile("s_waitcnt vmcnt(" #n ")" ::: "memory")
#define MEMBAR() asm volatile("" ::: "memory")

// ---- Stage 1: v-MLP. One wave = one head. Triple-buffered LDS x-tile,
// prefetch distance 2, exact counted vmcnt, COMPILE-TIME buffer indices.
__global__ __launch_bounds__(256) void k_stage1(
    const float* __restrict__ mem, const float* __restrict__ dim_pe,
    const float* __restrict__ W1, const float* __restrict__ b1,
    const float* __restrict__ W2, const float* __restrict__ b2,
    _Float16* __restrict__ vbuf)
{
    __shared__ float stage[4][3][1024];   // [wave][buf][16 rows x 64 cols]  48 KB

    const int blk = blockIdx.x;                 // ((b*CL + cl)*NTCH + tch)*4 + nhg
    const int nhg  = blk & 3;
    const int tch  = (blk >> 2) % NTCH_;
    const int rest = (blk >> 2) / NTCH_;
    const int cl   = rest & (CL_ - 1);
    const int b    = rest >> 4;
    const int lane = threadIdx.x & 63;
    const int wv   = threadIdx.x >> 6;
    const int nh   = nhg * 4 + wv;
    const int g    = lane >> 4;                 // k-group; also output ct owner
    const int fl   = lane & 15;
    const int kbase = (8 * g) & 15;             // g0->cr0-7, g1->cr8-15, dup for g2/g3
    const bool klive = (g < 2);                 // lower-K lanes carry x; upper-K carry pe

    const float* membase = mem + (long)b * MEMROWS_ * D_;
    _Float16* vrow = vbuf + (long)(b * CL_ + cl) * T_ * D_;
    const int t0 = tch * TCH_;

    // pe fragments (f16, loop-invariant B upper-K content; NOT halved - pairs with W1/2)
    h16x8 peq[4];
#pragma unroll
    for (int ct = 0; ct < 4; ++ct) {
        const int d0 = nh * DH_ + ct * 16 + fl;
        float p0 = dim_pe[(kbase + 0) * D_ + d0];
        float p1 = dim_pe[(kbase + 1) * D_ + d0];
        float p2 = dim_pe[(kbase + 2) * D_ + d0];
        float p3 = dim_pe[(kbase + 3) * D_ + d0];
        float p4 = dim_pe[(kbase + 4) * D_ + d0];
        float p5 = dim_pe[(kbase + 5) * D_ + d0];
        float p6 = dim_pe[(kbase + 6) * D_ + d0];
        float p7 = dim_pe[(kbase + 7) * D_ + d0];
        peq[ct] = packH4(cvt_pk(p0, p1), cvt_pk(p2, p3), cvt_pk(p4, p5), cvt_pk(p6, p7));
    }

    // W1^T A-fragments PRE-HALVED; b1/2 in MFMA C; W2 packed f16.
    h16x8 bfragA[4];
    f32x4 ci[4];
    h16x2 w2pk[8];
#pragma unroll
    for (int cn = 0; cn < 4; ++cn) {
        h16x2 q[4];
#pragma unroll
        for (int jp = 0; jp < 4; ++jp) {
            float w0 = 0.5f * W1[(nh * CRv_ + kbase + 2 * jp + 0) * HID_ + cn * 16 + fl];
            float w1 = 0.5f * W1[(nh * CRv_ + kbase + 2 * jp + 1) * HID_ + cn * 16 + fl];
            h16x2 qq; qq[0] = (_Float16)w0; qq[1] = (_Float16)w1;
            q[jp] = qq;
        }
        bfragA[cn] = packH4(q[0], q[1], q[2], q[3]);
#pragma unroll
        for (int r = 0; r < 4; ++r) ci[cn][r] = 0.5f * b1[nh * HID_ + cn * 16 + 4 * g + r];
        h16x2 wlo; wlo[0] = (_Float16)W2[nh * HID_ + cn * 16 + 4 * g + 0];
                   wlo[1] = (_Float16)W2[nh * HID_ + cn * 16 + 4 * g + 1];
        h16x2 whi; whi[0] = (_Float16)W2[nh * HID_ + cn * 16 + 4 * g + 2];
                   whi[1] = (_Float16)W2[nh * HID_ + cn * 16 + 4 * g + 3];
        w2pk[2 * cn + 0] = wlo;
        w2pk[2 * cn + 1] = whi;
    }
    const float b2s = b2[nh];
    const unsigned b2p = __builtin_bit_cast(unsigned, __builtin_amdgcn_cvt_pkrtz(b2s, b2s));

    // Staging pointers: instruction i loads rows i*4 + lane/16, col-quad lane%16.
    const int srow = lane >> 4;
    const int scol = (lane & 15) * 4;
    const float* gpa = membase + ((size_t)(cl * CRv_ +  0 + srow) * T_ + t0) * D_ + nh * DH_ + scol;
    const float* gpb = membase + ((size_t)(cl * CRv_ +  4 + srow) * T_ + t0) * D_ + nh * DH_ + scol;
    const float* gpc = membase + ((size_t)(cl * CRv_ +  8 + srow) * T_ + t0) * D_ + nh * DH_ + scol;
    const float* gpd = membase + ((size_t)(cl * CRv_ + 12 + srow) * T_ + t0) * D_ + nh * DH_ + scol;

    float* const lbase = &stage[wv][0][0];

#define ISSUE(bi) do { \
    float* lb = lbase + (bi) * 1024; \
    __builtin_amdgcn_global_load_lds((const AS1 void*)gpa, (AS3 void*)(lb + 0 * 256), 16, 0, 0); \
    __builtin_amdgcn_global_load_lds((const AS1 void*)gpb, (AS3 void*)(lb + 1 * 256), 16, 0, 0); \
    __builtin_amdgcn_global_load_lds((const AS1 void*)gpc, (AS3 void*)(lb + 2 * 256), 16, 0, 0); \
    __builtin_amdgcn_global_load_lds((const AS1 void*)gpd, (AS3 void*)(lb + 3 * 256), 16, 0, 0); \
    gpa += D_; gpb += D_; gpc += D_; gpd += D_; } while (0)

    int tcur = t0;

#define BODY(IB, WN, DOISS, IBN) do { \
    if (DOISS) ISSUE(IBN); \
    WAITV(WN); \
    const float* bufp = lbase + (IB) * 1024; \
    float prl[4]; \
    _Pragma("unroll") \
    for (int ct = 0; ct < 4; ++ct) { \
        float a0 = bufp[(kbase + 0) * 64 + ct * 16 + fl]; \
        float a1 = bufp[(kbase + 1) * 64 + ct * 16 + fl]; \
        float a2 = bufp[(kbase + 2) * 64 + ct * 16 + fl]; \
        float a3 = bufp[(kbase + 3) * 64 + ct * 16 + fl]; \
        float a4 = bufp[(kbase + 4) * 64 + ct * 16 + fl]; \
        float a5 = bufp[(kbase + 5) * 64 + ct * 16 + fl]; \
        float a6 = bufp[(kbase + 6) * 64 + ct * 16 + fl]; \
        float a7 = bufp[(kbase + 7) * 64 + ct * 16 + fl]; \
        h16x8 xq = packH4(cvt_pk(a0, a1), cvt_pk(a2, a3), cvt_pk(a4, a5), cvt_pk(a6, a7)); \
        h16x8 af = klive ? xq : peq[ct]; \
        f32x4 acc[4]; \
        _Pragma("unroll") \
        for (int cn = 0; cn < 4; ++cn) \
            acc[cn] = __builtin_amdgcn_mfma_f32_16x16x32_f16(bfragA[cn], af, ci[cn], 0, 0, 0); \
        h16x2 pc0 = hsplat(0.f), pc1 = hsplat(0.f); \
        _Pragma("unroll") \
        for (int cn = 0; cn < 4; ++cn) { \
            h16x2 a01 = cvt_pk(acc[cn][0], acc[cn][1]); \
            h16x2 a23 = cvt_pk(acc[cn][2], acc[cn][3]); \
            gelu_w2_pk(a01, w2pk[2 * cn + 0], pc0); \
            gelu_w2_pk(a23, w2pk[2 * cn + 1], pc1); \
        } \
        h16x2 P = pc0 + pc1; \
        prl[ct] = (float)P[0] + (float)P[1]; \
    } \
    unsigned A  = __builtin_bit_cast(unsigned, __builtin_amdgcn_cvt_pkrtz(prl[0], prl[1])); \
    unsigned Bp = __builtin_bit_cast(unsigned, __builtin_amdgcn_cvt_pkrtz(prl[2], prl[3])); \
    A  = pkadd(A,  (unsigned)__shfl_xor((int)A, 16)); \
    Bp = pkadd(Bp, (unsigned)__shfl_xor((int)Bp, 16)); \
    A  = pkadd(A,  (unsigned)__shfl_xor((int)A, 32)); \
    Bp = pkadd(Bp, (unsigned)__shfl_xor((int)Bp, 32)); \
    A  = pkadd(A, b2p); \
    Bp = pkadd(Bp, b2p); \
    unsigned sel = (g < 2) ? A : Bp; \
    unsigned sh  = (g & 1) ? (sel >> 16) : sel; \
    vrow[(size_t)tcur * D_ + nh * DH_ + g * 16 + fl] = \
        __builtin_bit_cast(_Float16, (unsigned short)sh); \
    MEMBAR(); \
    ++tcur; \
} while (0)

    ISSUE(0);                 // L(t0) -> buf0
    ISSUE(1);                 // L(t1) -> buf1
    BODY(0, 8, 1, 2);         // tt=0: issue L2->buf2
    BODY(1, 9, 1, 0);         // tt=1: issue L3->buf0
#pragma unroll 1
    for (int tb = 0; tb < 7; ++tb) {   // tt = 2+3tb .. 4+3tb  (tt=2..22)
        BODY(2, 10, 1, 1);
        BODY(0, 10, 1, 2);
        BODY(1, 10, 1, 0);
    }
    BODY(2, 6, 0, 0);         // tt=23
    BODY(0, 2, 0, 0);         // tt=24
#undef BODY
#undef ISSUE
}

// ---- Stage 2: h-MLP over t = tc*16+cr (pad rows -> nonsense). Pre-halved W1/b1.
__global__ __launch_bounds__(256) void k_stage2(
    const _Float16* __restrict__ vbuf, const float* __restrict__ mem,
    const float* __restrict__ W1, const float* __restrict__ b1,
    const float* __restrict__ W2, const float* __restrict__ b2,
    float* __restrict__ hbuf)
{
    const int blk = blockIdx.x;                // ((b*CL + cl)*16 + tc)*4 + nhg
    const int nhg = blk & 3;
    const int tc  = (blk >> 2) & 15;
    const int cl  = (blk >> 6) & 15;
    const int b   = blk >> 10;
    const int lane = threadIdx.x & 63;
    const int wv   = threadIdx.x >> 6;
    const int nh   = nhg * 4 + wv;
    const int g    = lane >> 4;
    const int fl   = lane & 15;
    const int kbase = (8 * g) & 15;
    const bool klive = (g < 2);

    const _Float16* vrow = vbuf + (long)(b * CL_ + cl) * T_ * D_;
    const float* nons = mem + ((long)b * MEMROWS_ + (long)L_ * T_) * D_;

    h16x8 bfragA[4];
    f32x4 ci[4];
    h16x2 w2pk[8];
#pragma unroll
    for (int cn = 0; cn < 4; ++cn) {
        h16x2 q[4];
#pragma unroll
        for (int jp = 0; jp < 4; ++jp) {
            float w0 = 0.5f * W1[(nh * CRv_ + kbase + 2 * jp + 0) * HID_ + cn * 16 + fl];
            float w1 = 0.5f * W1[(nh * CRv_ + kbase + 2 * jp + 1) * HID_ + cn * 16 + fl];
            h16x2 qq; qq[0] = klive ? (_Float16)w0 : (_Float16)0.f;
                      qq[1] = klive ? (_Float16)w1 : (_Float16)0.f;
            q[jp] = qq;
        }
        bfragA[cn] = packH4(q[0], q[1], q[2], q[3]);
#pragma unroll
        for (int r = 0; r < 4; ++r) ci[cn][r] = 0.5f * b1[nh * HID_ + cn * 16 + 4 * g + r];
        h16x2 wlo; wlo[0] = (_Float16)W2[nh * HID_ + cn * 16 + 4 * g + 0];
                   wlo[1] = (_Float16)W2[nh * HID_ + cn * 16 + 4 * g + 1];
        h16x2 whi; whi[0] = (_Float16)W2[nh * HID_ + cn * 16 + 4 * g + 2];
                   whi[1] = (_Float16)W2[nh * HID_ + cn * 16 + 4 * g + 3];
        w2pk[2 * cn + 0] = wlo;
        w2pk[2 * cn + 1] = whi;
    }
    const float b2s = b2[nh];

#pragma unroll 1
    for (int ct = 0; ct < 4; ++ct) {
        const int d0 = nh * DH_ + ct * 16 + fl;
        const _Float16 nv = (_Float16)nons[d0];

        h16x2 q[4];
#pragma unroll
        for (int jp = 0; jp < 4; ++jp) {
            h16x2 qq;
#pragma unroll
            for (int e = 0; e < 2; ++e) {
                const int t   = tc * CRv_ + kbase + 2 * jp + e;
                const int tcl = (t < T_) ? t : (T_ - 1);
                _Float16 us = vrow[tcl * D_ + d0];
                qq[e] = (t < T_) ? us : nv;
            }
            q[jp] = qq;
        }
        h16x8 af = packH4(q[0], q[1], q[2], q[3]);

        f32x4 acc[4];
#pragma unroll
        for (int cn = 0; cn < 4; ++cn)
            acc[cn] = __builtin_amdgcn_mfma_f32_16x16x32_f16(bfragA[cn], af, ci[cn], 0, 0, 0);

        h16x2 pc0 = hsplat(0.f), pc1 = hsplat(0.f);
#pragma unroll
        for (int cn = 0; cn < 4; ++cn) {
            h16x2 a01 = cvt_pk(acc[cn][0], acc[cn][1]);
            h16x2 a23 = cvt_pk(acc[cn][2], acc[cn][3]);
            gelu_w2_pk(a01, w2pk[2 * cn + 0], pc0);
            gelu_w2_pk(a23, w2pk[2 * cn + 1], pc1);
        }
        float pr = ((float)pc0[0] + (float)pc0[1]) + ((float)pc1[0] + (float)pc1[1]);
        pr += __shfl_xor(pr, 16);
        pr += __shfl_xor(pr, 32);

        if (g == 0)
            hbuf[(long)((b * CL_ + cl) * 16 + tc) * D_ + d0] = pr + b2s;
    }
}

// ---- Stage 3: C(512x1024) = H @ projW^T + bias (fp32 tiled GEMM)
__global__ __launch_bounds__(256) void k_proj(
    const float* __restrict__ H, const float* __restrict__ Wp,
    const float* __restrict__ bias, float* __restrict__ Cout)
{
    constexpr int BM = 32, BN = 64, BK = 32, K = 1024, NCOLB = OUT_ / BN; // 16
    __shared__ float Ht[BM][BK + 1];
    __shared__ float Wt[BN][BK + 1];

    const int bn = blockIdx.x % NCOLB;
    const int bm = blockIdx.x / NCOLB;
    const int tid = threadIdx.x;
    const int tx = tid & 15;
    const int ty = tid >> 4;
    const int lr = tid >> 3;
    const int lc = (tid & 7) << 2;

    float acc[2][4] = {};

    for (int k0 = 0; k0 < K; k0 += BK) {
        float4 hv  = *(const float4*)(H  + (long)(bm * BM + lr) * K + k0 + lc);
        float4 w0  = *(const float4*)(Wp + (long)(bn * BN + lr) * K + k0 + lc);
        float4 w1v = *(const float4*)(Wp + (long)(bn * BN + 32 + lr) * K + k0 + lc);
        Ht[lr][lc + 0] = hv.x;  Ht[lr][lc + 1] = hv.y;  Ht[lr][lc + 2] = hv.z;  Ht[lr][lc + 3] = hv.w;
        Wt[lr][lc + 0] = w0.x;  Wt[lr][lc + 1] = w0.y;  Wt[lr][lc + 2] = w0.z;  Wt[lr][lc + 3] = w0.w;
        Wt[32 + lr][lc + 0] = w1v.x; Wt[32 + lr][lc + 1] = w1v.y; Wt[32 + lr][lc + 2] = w1v.z; Wt[32 + lr][lc + 3] = w1v.w;
        __syncthreads();

#pragma unroll
        for (int kk = 0; kk < BK; ++kk) {
            float va0 = Ht[ty * 2 + 0][kk];
            float va1 = Ht[ty * 2 + 1][kk];
            float vb0 = Wt[tx * 4 + 0][kk];
            float vb1 = Wt[tx * 4 + 1][kk];
            float vb2 = Wt[tx * 4 + 2][kk];
            float vb3 = Wt[tx * 4 + 3][kk];
            acc[0][0] = fmaf(va0, vb0, acc[0][0]);
            acc[0][1] = fmaf(va0, vb1, acc[0][1]);
            acc[0][2] = fmaf(va0, vb2, acc[0][2]);
            acc[0][3] = fmaf(va0, vb3, acc[0][3]);
            acc[1][0] = fmaf(va1, vb0, acc[1][0]);
            acc[1][1] = fmaf(va1, vb1, acc[1][1]);
            acc[1][2] = fmaf(va1, vb2, acc[1][2]);
            acc[1][3] = fmaf(va1, vb3, acc[1][3]);
        }
        __syncthreads();
    }

#pragma unroll
    for (int i = 0; i < 2; ++i) {
#pragma unroll
        for (int jj = 0; jj < 4; ++jj) {
            int r = bm * BM + ty * 2 + i;
            int c = bn * BN + tx * 4 + jj;
            Cout[(long)r * OUT_ + c] = acc[i][jj] + bias[c];
        }
    }
}

extern "C" void kernel_launch(void* const* d_in, const int* in_sizes, int n_in,
                              void* d_out, int out_size, void* d_ws, size_t ws_size,
                              hipStream_t stream) {
    const float* mem    = (const float*)d_in[0];
    const float* dim_pe = (const float*)d_in[2];
    const float* vW1    = (const float*)d_in[3];
    const float* vb1    = (const float*)d_in[4];
    const float* vW2    = (const float*)d_in[5];
    const float* vb2    = (const float*)d_in[6];
    const float* hW1    = (const float*)d_in[7];
    const float* hb1    = (const float*)d_in[8];
    const float* hW2    = (const float*)d_in[9];
    const float* hb2    = (const float*)d_in[10];
    const float* projW  = (const float*)d_in[11];
    const float* projb  = (const float*)d_in[12];
    float* out = (float*)d_out;

    _Float16* vbuf = (_Float16*)d_ws;                                   // f16, 16 MB
    float* hbuf = (float*)((char*)d_ws + (size_t)B_ * CL_ * T_ * D_ * sizeof(_Float16));

    k_stage1<<<B_ * CL_ * NTCH_ * 4, 256, 0, stream>>>(mem, dim_pe, vW1, vb1, vW2, vb2, vbuf);
    k_stage2<<<B_ * CL_ * 16 * 4, 256, 0, stream>>>(vbuf, mem, hW1, hb1, hW2, hb2, hbuf);
    k_proj<<<(512 / 32) * (OUT_ / 64), 256, 0, stream>>>(hbuf, projW, projb, out);
}

// Round 11
// 220.462 us; speedup vs baseline: 1.0175x; 1.0175x over previous
//
#include <hip/hip_runtime.h>
#include <hip/hip_bf16.h>

#define B_ 2
#define L_ 256
#define T_ 250
#define D_ 1024
#define NH_ 16
#define DH_ 64
#define CRv_ 16
#define HID_ 64
#define CL_ 16
#define OUT_ 1024
#define MEMROWS_ 64001L
#define TCH_ 25
#define NTCH_ (T_ / TCH_)   // 10

#define AS1 __attribute__((address_space(1)))
#define AS3 __attribute__((address_space(3)))

typedef __attribute__((ext_vector_type(2))) _Float16 h16x2;
typedef __attribute__((ext_vector_type(8))) _Float16 h16x8;
typedef __attribute__((ext_vector_type(4))) float f32x4;

__device__ __forceinline__ h16x2 cvt_pk(float lo, float hi) {
    return __builtin_bit_cast(h16x2, __builtin_amdgcn_cvt_pkrtz(lo, hi));
}
__device__ __forceinline__ unsigned cvt_pku(float lo, float hi) {
    return __builtin_bit_cast(unsigned, __builtin_amdgcn_cvt_pkrtz(lo, hi));
}

struct H4 { h16x2 a, b, c, d; };
__device__ __forceinline__ h16x8 packH4(h16x2 a, h16x2 b, h16x2 c, h16x2 d) {
    H4 h{a, b, c, d};
    return __builtin_bit_cast(h16x8, h);
}

// ---- guaranteed-VOP3P packed f16 ops (inline asm; defeats scalarization) ----
__device__ __forceinline__ unsigned pk_fma(unsigned a, unsigned b, unsigned c) {
    unsigned d; asm("v_pk_fma_f16 %0, %1, %2, %3" : "=v"(d) : "v"(a), "v"(b), "v"(c)); return d;
}
__device__ __forceinline__ unsigned pk_mul(unsigned a, unsigned b) {
    unsigned d; asm("v_pk_mul_f16 %0, %1, %2" : "=v"(d) : "v"(a), "v"(b)); return d;
}
__device__ __forceinline__ unsigned pk_add(unsigned a, unsigned b) {
    unsigned d; asm("v_pk_add_f16 %0, %1, %2" : "=v"(d) : "v"(a), "v"(b)); return d;
}
__device__ __forceinline__ unsigned pk_max(unsigned a, unsigned b) {
    unsigned d; asm("v_pk_max_f16 %0, %1, %2" : "=v"(d) : "v"(a), "v"(b)); return d;
}
__device__ __forceinline__ unsigned pk_min(unsigned a, unsigned b) {
    unsigned d; asm("v_pk_min_f16 %0, %1, %2" : "=v"(d) : "v"(a), "v"(b)); return d;
}

// gelu poly constants, splatted once into VGPRs
struct GC { unsigned c0, c1, c2, c3, c4, clo, chi; };
__device__ __forceinline__ GC make_gc() {
    GC g;
    g.c0  = cvt_pku( 1.5957600f,   1.5957600f);
    g.c1  = cvt_pku(-1.0445624f,  -1.0445624f);
    g.c2  = cvt_pku( 0.5417632f,   0.5417632f);
    g.c3  = cvt_pku(-0.15817472f, -0.15817472f);
    g.c4  = cvt_pku( 0.018604288f, 0.018604288f);
    g.clo = cvt_pku(-1.75f, -1.75f);
    g.chi = cvt_pku( 1.75f,  1.75f);
    return g;
}

// Packed-f16 gelu * w2 accumulate, PRE-HALVED input aH = x/2. 10 VOP3P ops / 2 values.
__device__ __forceinline__ void gelu_w2_asm(unsigned aH, unsigned w, unsigned& pacc, const GC& gc) {
    unsigned t = pk_min(pk_max(aH, gc.clo), gc.chi);
    unsigned s = pk_mul(t, t);
    unsigned p = pk_fma(gc.c4, s, gc.c3);
    p = pk_fma(p, s, gc.c2);
    p = pk_fma(p, s, gc.c1);
    p = pk_fma(p, s, gc.c0);
    unsigned e = pk_mul(t, p);
    unsigned g = pk_fma(aH, e, aH);
    pacc = pk_fma(g, w, pacc);
}

#define WAITV(n) asm volatile("s_waitcnt vmcnt(" #n ")" ::: "memory")
#define MEMBAR() asm volatile("" ::: "memory")

// ---- Stage 1: v-MLP. One wave = one head. Triple-buffered LDS x-tile,
// prefetch distance 2, exact counted vmcnt, compile-time buffer indices.
__global__ __launch_bounds__(256) void k_stage1(
    const float* __restrict__ mem, const float* __restrict__ dim_pe,
    const float* __restrict__ W1, const float* __restrict__ b1,
    const float* __restrict__ W2, const float* __restrict__ b2,
    _Float16* __restrict__ vbuf)
{
    __shared__ float stage[4][3][1024];   // [wave][buf][16 rows x 64 cols]  48 KB

    const int blk = blockIdx.x;                 // ((b*CL + cl)*NTCH + tch)*4 + nhg
    const int nhg  = blk & 3;
    const int tch  = (blk >> 2) % NTCH_;
    const int rest = (blk >> 2) / NTCH_;
    const int cl   = rest & (CL_ - 1);
    const int b    = rest >> 4;
    const int lane = threadIdx.x & 63;
    const int wv   = threadIdx.x >> 6;
    const int nh   = nhg * 4 + wv;
    const int g    = lane >> 4;                 // k-group; also output ct owner
    const int fl   = lane & 15;
    const int kbase = (8 * g) & 15;             // g0->cr0-7, g1->cr8-15, dup for g2/g3
    const bool klive = (g < 2);                 // lower-K lanes carry x; upper-K carry pe

    const float* membase = mem + (long)b * MEMROWS_ * D_;
    _Float16* vrow = vbuf + (long)(b * CL_ + cl) * T_ * D_;
    const int t0 = tch * TCH_;

    const GC gc = make_gc();

    // pe fragments (f16, loop-invariant B upper-K content; NOT halved - pairs with W1/2)
    h16x8 peq[4];
#pragma unroll
    for (int ct = 0; ct < 4; ++ct) {
        const int d0 = nh * DH_ + ct * 16 + fl;
        float p0 = dim_pe[(kbase + 0) * D_ + d0];
        float p1 = dim_pe[(kbase + 1) * D_ + d0];
        float p2 = dim_pe[(kbase + 2) * D_ + d0];
        float p3 = dim_pe[(kbase + 3) * D_ + d0];
        float p4 = dim_pe[(kbase + 4) * D_ + d0];
        float p5 = dim_pe[(kbase + 5) * D_ + d0];
        float p6 = dim_pe[(kbase + 6) * D_ + d0];
        float p7 = dim_pe[(kbase + 7) * D_ + d0];
        peq[ct] = packH4(cvt_pk(p0, p1), cvt_pk(p2, p3), cvt_pk(p4, p5), cvt_pk(p6, p7));
    }

    // W1^T A-fragments PRE-HALVED; b1/2 in MFMA C; W2 packed u32.
    h16x8 bfragA[4];
    f32x4 ci[4];
    unsigned w2u[8];
#pragma unroll
    for (int cn = 0; cn < 4; ++cn) {
        h16x2 q[4];
#pragma unroll
        for (int jp = 0; jp < 4; ++jp) {
            float w0 = 0.5f * W1[(nh * CRv_ + kbase + 2 * jp + 0) * HID_ + cn * 16 + fl];
            float w1 = 0.5f * W1[(nh * CRv_ + kbase + 2 * jp + 1) * HID_ + cn * 16 + fl];
            q[jp] = cvt_pk(w0, w1);
        }
        bfragA[cn] = packH4(q[0], q[1], q[2], q[3]);
#pragma unroll
        for (int r = 0; r < 4; ++r) ci[cn][r] = 0.5f * b1[nh * HID_ + cn * 16 + 4 * g + r];
        w2u[2 * cn + 0] = cvt_pku(W2[nh * HID_ + cn * 16 + 4 * g + 0],
                                  W2[nh * HID_ + cn * 16 + 4 * g + 1]);
        w2u[2 * cn + 1] = cvt_pku(W2[nh * HID_ + cn * 16 + 4 * g + 2],
                                  W2[nh * HID_ + cn * 16 + 4 * g + 3]);
    }
    const float b2s = b2[nh];
    const unsigned b2p = cvt_pku(b2s, b2s);

    // Staging pointers: instruction i loads rows i*4 + lane/16, col-quad lane%16.
    const int srow = lane >> 4;
    const int scol = (lane & 15) * 4;
    const float* gpa = membase + ((size_t)(cl * CRv_ +  0 + srow) * T_ + t0) * D_ + nh * DH_ + scol;
    const float* gpb = membase + ((size_t)(cl * CRv_ +  4 + srow) * T_ + t0) * D_ + nh * DH_ + scol;
    const float* gpc = membase + ((size_t)(cl * CRv_ +  8 + srow) * T_ + t0) * D_ + nh * DH_ + scol;
    const float* gpd = membase + ((size_t)(cl * CRv_ + 12 + srow) * T_ + t0) * D_ + nh * DH_ + scol;

    float* const lbase = &stage[wv][0][0];

#define ISSUE(bi) do { \
    float* lb = lbase + (bi) * 1024; \
    __builtin_amdgcn_global_load_lds((const AS1 void*)gpa, (AS3 void*)(lb + 0 * 256), 16, 0, 0); \
    __builtin_amdgcn_global_load_lds((const AS1 void*)gpb, (AS3 void*)(lb + 1 * 256), 16, 0, 0); \
    __builtin_amdgcn_global_load_lds((const AS1 void*)gpc, (AS3 void*)(lb + 2 * 256), 16, 0, 0); \
    __builtin_amdgcn_global_load_lds((const AS1 void*)gpd, (AS3 void*)(lb + 3 * 256), 16, 0, 0); \
    gpa += D_; gpb += D_; gpc += D_; gpd += D_; } while (0)

    int tcur = t0;

#define BODY(IB, WN, DOISS, IBN) do { \
    if (DOISS) ISSUE(IBN); \
    WAITV(WN); \
    const float* bufp = lbase + (IB) * 1024; \
    float prl[4]; \
    _Pragma("unroll") \
    for (int ct = 0; ct < 4; ++ct) { \
        float a0 = bufp[(kbase + 0) * 64 + ct * 16 + fl]; \
        float a1 = bufp[(kbase + 1) * 64 + ct * 16 + fl]; \
        float a2 = bufp[(kbase + 2) * 64 + ct * 16 + fl]; \
        float a3 = bufp[(kbase + 3) * 64 + ct * 16 + fl]; \
        float a4 = bufp[(kbase + 4) * 64 + ct * 16 + fl]; \
        float a5 = bufp[(kbase + 5) * 64 + ct * 16 + fl]; \
        float a6 = bufp[(kbase + 6) * 64 + ct * 16 + fl]; \
        float a7 = bufp[(kbase + 7) * 64 + ct * 16 + fl]; \
        h16x8 xq = packH4(cvt_pk(a0, a1), cvt_pk(a2, a3), cvt_pk(a4, a5), cvt_pk(a6, a7)); \
        h16x8 af = klive ? xq : peq[ct]; \
        f32x4 acc[4]; \
        _Pragma("unroll") \
        for (int cn = 0; cn < 4; ++cn) \
            acc[cn] = __builtin_amdgcn_mfma_f32_16x16x32_f16(bfragA[cn], af, ci[cn], 0, 0, 0); \
        unsigned pc0 = 0u, pc1 = 0u; \
        _Pragma("unroll") \
        for (int cn = 0; cn < 4; ++cn) { \
            unsigned a01 = cvt_pku(acc[cn][0], acc[cn][1]); \
            unsigned a23 = cvt_pku(acc[cn][2], acc[cn][3]); \
            gelu_w2_asm(a01, w2u[2 * cn + 0], pc0, gc); \
            gelu_w2_asm(a23, w2u[2 * cn + 1], pc1, gc); \
        } \
        h16x2 P = __builtin_bit_cast(h16x2, pk_add(pc0, pc1)); \
        prl[ct] = (float)P[0] + (float)P[1]; \
    } \
    unsigned A  = cvt_pku(prl[0], prl[1]); \
    unsigned Bp = cvt_pku(prl[2], prl[3]); \
    A  = pk_add(A,  (unsigned)__shfl_xor((int)A, 16)); \
    Bp = pk_add(Bp, (unsigned)__shfl_xor((int)Bp, 16)); \
    A  = pk_add(A,  (unsigned)__shfl_xor((int)A, 32)); \
    Bp = pk_add(Bp, (unsigned)__shfl_xor((int)Bp, 32)); \
    A  = pk_add(A, b2p); \
    Bp = pk_add(Bp, b2p); \
    unsigned sel = (g < 2) ? A : Bp; \
    unsigned sh  = (g & 1) ? (sel >> 16) : sel; \
    vrow[(size_t)tcur * D_ + nh * DH_ + g * 16 + fl] = \
        __builtin_bit_cast(_Float16, (unsigned short)sh); \
    MEMBAR(); \
    ++tcur; \
} while (0)

    ISSUE(0);                 // L(t0) -> buf0
    ISSUE(1);                 // L(t1) -> buf1
    BODY(0, 8, 1, 2);         // tt=0: issue L2->buf2
    BODY(1, 9, 1, 0);         // tt=1: issue L3->buf0
#pragma unroll 1
    for (int tb = 0; tb < 7; ++tb) {   // tt = 2..22
        BODY(2, 10, 1, 1);
        BODY(0, 10, 1, 2);
        BODY(1, 10, 1, 0);
    }
    BODY(2, 6, 0, 0);         // tt=23
    BODY(0, 2, 0, 0);         // tt=24
#undef BODY
#undef ISSUE
}

// ---- Stage 2: h-MLP over t = tc*16+cr (pad rows -> nonsense). Pre-halved W1/b1.
__global__ __launch_bounds__(256) void k_stage2(
    const _Float16* __restrict__ vbuf, const float* __restrict__ mem,
    const float* __restrict__ W1, const float* __restrict__ b1,
    const float* __restrict__ W2, const float* __restrict__ b2,
    float* __restrict__ hbuf)
{
    const int blk = blockIdx.x;                // ((b*CL + cl)*16 + tc)*4 + nhg
    const int nhg = blk & 3;
    const int tc  = (blk >> 2) & 15;
    const int cl  = (blk >> 6) & 15;
    const int b   = blk >> 10;
    const int lane = threadIdx.x & 63;
    const int wv   = threadIdx.x >> 6;
    const int nh   = nhg * 4 + wv;
    const int g    = lane >> 4;
    const int fl   = lane & 15;
    const int kbase = (8 * g) & 15;
    const bool klive = (g < 2);

    const _Float16* vrow = vbuf + (long)(b * CL_ + cl) * T_ * D_;
    const float* nons = mem + ((long)b * MEMROWS_ + (long)L_ * T_) * D_;

    const GC gc = make_gc();

    h16x8 bfragA[4];
    f32x4 ci[4];
    unsigned w2u[8];
#pragma unroll
    for (int cn = 0; cn < 4; ++cn) {
        h16x2 q[4];
#pragma unroll
        for (int jp = 0; jp < 4; ++jp) {
            float w0 = 0.5f * W1[(nh * CRv_ + kbase + 2 * jp + 0) * HID_ + cn * 16 + fl];
            float w1 = 0.5f * W1[(nh * CRv_ + kbase + 2 * jp + 1) * HID_ + cn * 16 + fl];
            h16x2 qq = cvt_pk(w0, w1);
            if (!klive) { qq[0] = (_Float16)0.f; qq[1] = (_Float16)0.f; }
            q[jp] = qq;
        }
        bfragA[cn] = packH4(q[0], q[1], q[2], q[3]);
#pragma unroll
        for (int r = 0; r < 4; ++r) ci[cn][r] = 0.5f * b1[nh * HID_ + cn * 16 + 4 * g + r];
        w2u[2 * cn + 0] = cvt_pku(W2[nh * HID_ + cn * 16 + 4 * g + 0],
                                  W2[nh * HID_ + cn * 16 + 4 * g + 1]);
        w2u[2 * cn + 1] = cvt_pku(W2[nh * HID_ + cn * 16 + 4 * g + 2],
                                  W2[nh * HID_ + cn * 16 + 4 * g + 3]);
    }
    const float b2s = b2[nh];

#pragma unroll 1
    for (int ct = 0; ct < 4; ++ct) {
        const int d0 = nh * DH_ + ct * 16 + fl;
        const _Float16 nv = (_Float16)nons[d0];

        h16x2 q[4];
#pragma unroll
        for (int jp = 0; jp < 4; ++jp) {
            h16x2 qq;
#pragma unroll
            for (int e = 0; e < 2; ++e) {
                const int t   = tc * CRv_ + kbase + 2 * jp + e;
                const int tcl = (t < T_) ? t : (T_ - 1);
                _Float16 us = vrow[tcl * D_ + d0];
                qq[e] = (t < T_) ? us : nv;
            }
            q[jp] = qq;
        }
        h16x8 af = packH4(q[0], q[1], q[2], q[3]);

        f32x4 acc[4];
#pragma unroll
        for (int cn = 0; cn < 4; ++cn)
            acc[cn] = __builtin_amdgcn_mfma_f32_16x16x32_f16(bfragA[cn], af, ci[cn], 0, 0, 0);

        unsigned pc0 = 0u, pc1 = 0u;
#pragma unroll
        for (int cn = 0; cn < 4; ++cn) {
            unsigned a01 = cvt_pku(acc[cn][0], acc[cn][1]);
            unsigned a23 = cvt_pku(acc[cn][2], acc[cn][3]);
            gelu_w2_asm(a01, w2u[2 * cn + 0], pc0, gc);
            gelu_w2_asm(a23, w2u[2 * cn + 1], pc1, gc);
        }
        h16x2 P = __builtin_bit_cast(h16x2, pk_add(pc0, pc1));
        float pr = (float)P[0] + (float)P[1];
        pr += __shfl_xor(pr, 16);
        pr += __shfl_xor(pr, 32);

        if (g == 0)
            hbuf[(long)((b * CL_ + cl) * 16 + tc) * D_ + d0] = pr + b2s;
    }
}

// ---- Stage 3: C(512x1024) = H @ projW^T + bias (fp32 tiled GEMM)
__global__ __launch_bounds__(256) void k_proj(
    const float* __restrict__ H, const float* __restrict__ Wp,
    const float* __restrict__ bias, float* __restrict__ Cout)
{
    constexpr int BM = 32, BN = 64, BK = 32, K = 1024, NCOLB = OUT_ / BN; // 16
    __shared__ float Ht[BM][BK + 1];
    __shared__ float Wt[BN][BK + 1];

    const int bn = blockIdx.x % NCOLB;
    const int bm = blockIdx.x / NCOLB;
    const int tid = threadIdx.x;
    const int tx = tid & 15;
    const int ty = tid >> 4;
    const int lr = tid >> 3;
    const int lc = (tid & 7) << 2;

    float acc[2][4] = {};

    for (int k0 = 0; k0 < K; k0 += BK) {
        float4 hv  = *(const float4*)(H  + (long)(bm * BM + lr) * K + k0 + lc);
        float4 w0  = *(const float4*)(Wp + (long)(bn * BN + lr) * K + k0 + lc);
        float4 w1v = *(const float4*)(Wp + (long)(bn * BN + 32 + lr) * K + k0 + lc);
        Ht[lr][lc + 0] = hv.x;  Ht[lr][lc + 1] = hv.y;  Ht[lr][lc + 2] = hv.z;  Ht[lr][lc + 3] = hv.w;
        Wt[lr][lc + 0] = w0.x;  Wt[lr][lc + 1] = w0.y;  Wt[lr][lc + 2] = w0.z;  Wt[lr][lc + 3] = w0.w;
        Wt[32 + lr][lc + 0] = w1v.x; Wt[32 + lr][lc + 1] = w1v.y; Wt[32 + lr][lc + 2] = w1v.z; Wt[32 + lr][lc + 3] = w1v.w;
        __syncthreads();

#pragma unroll
        for (int kk = 0; kk < BK; ++kk) {
            float va0 = Ht[ty * 2 + 0][kk];
            float va1 = Ht[ty * 2 + 1][kk];
            float vb0 = Wt[tx * 4 + 0][kk];
            float vb1 = Wt[tx * 4 + 1][kk];
            float vb2 = Wt[tx * 4 + 2][kk];
            float vb3 = Wt[tx * 4 + 3][kk];
            acc[0][0] = fmaf(va0, vb0, acc[0][0]);
            acc[0][1] = fmaf(va0, vb1, acc[0][1]);
            acc[0][2] = fmaf(va0, vb2, acc[0][2]);
            acc[0][3] = fmaf(va0, vb3, acc[0][3]);
            acc[1][0] = fmaf(va1, vb0, acc[1][0]);
            acc[1][1] = fmaf(va1, vb1, acc[1][1]);
            acc[1][2] = fmaf(va1, vb2, acc[1][2]);
            acc[1][3] = fmaf(va1, vb3, acc[1][3]);
        }
        __syncthreads();
    }

#pragma unroll
    for (int i = 0; i < 2; ++i) {
#pragma unroll
        for (int jj = 0; jj < 4; ++jj) {
            int r = bm * BM + ty * 2 + i;
            int c = bn * BN + tx * 4 + jj;
            Cout[(long)r * OUT_ + c] = acc[i][jj] + bias[c];
        }
    }
}

extern "C" void kernel_launch(void* const* d_in, const int* in_sizes, int n_in,
                              void* d_out, int out_size, void* d_ws, size_t ws_size,
                              hipStream_t stream) {
    const float* mem    = (const float*)d_in[0];
    const float* dim_pe = (const float*)d_in[2];
    const float* vW1    = (const float*)d_in[3];
    const float* vb1    = (const float*)d_in[4];
    const float* vW2    = (const float*)d_in[5];
    const float* vb2    = (const float*)d_in[6];
    const float* hW1    = (const float*)d_in[7];
    const float* hb1    = (const float*)d_in[8];
    const float* hW2    = (const float*)d_in[9];
    const float* hb2    = (const float*)d_in[10];
    const float* projW  = (const float*)d_in[11];
    const float* projb  = (const float*)d_in[12];
    float* out = (float*)d_out;

    _Float16* vbuf = (_Float16*)d_ws;                                   // f16, 16 MB
    float* hbuf = (float*)((char*)d_ws + (size_t)B_ * CL_ * T_ * D_ * sizeof(_Float16));

    k_stage1<<<B_ * CL_ * NTCH_ * 4, 256, 0, stream>>>(mem, dim_pe, vW1, vb1, vW2, vb2, vbuf);
    k_stage2<<<B_ * CL_ * 16 * 4, 256, 0, stream>>>(vbuf, mem, hW1, hb1, hW2, hb2, hbuf);
    k_proj<<<(512 / 32) * (OUT_ / 64), 256, 0, stream>>>(hbuf, projW, projb, out);
}

// Round 12
// 216.856 us; speedup vs baseline: 1.0344x; 1.0166x over previous
//
#include <hip/hip_runtime.h>
#include <hip/hip_bf16.h>

#define B_ 2
#define L_ 256
#define T_ 250
#define D_ 1024
#define NH_ 16
#define DH_ 64
#define CRv_ 16
#define HID_ 64
#define CL_ 16
#define OUT_ 1024
#define MEMROWS_ 64001L

#define AS1 __attribute__((address_space(1)))
#define AS3 __attribute__((address_space(3)))

typedef __attribute__((ext_vector_type(2))) _Float16 h16x2;
typedef __attribute__((ext_vector_type(8))) _Float16 h16x8;
typedef __attribute__((ext_vector_type(4))) float f32x4;

__device__ __forceinline__ h16x2 cvt_pk(float lo, float hi) {
    return __builtin_bit_cast(h16x2, __builtin_amdgcn_cvt_pkrtz(lo, hi));
}
__device__ __forceinline__ unsigned cvt_pku(float lo, float hi) {
    return __builtin_bit_cast(unsigned, __builtin_amdgcn_cvt_pkrtz(lo, hi));
}

struct H4 { h16x2 a, b, c, d; };
__device__ __forceinline__ h16x8 packH4(h16x2 a, h16x2 b, h16x2 c, h16x2 d) {
    H4 h{a, b, c, d};
    return __builtin_bit_cast(h16x8, h);
}

// ---- guaranteed-VOP3P packed f16 ops ----
__device__ __forceinline__ unsigned pk_fma(unsigned a, unsigned b, unsigned c) {
    unsigned d; asm("v_pk_fma_f16 %0, %1, %2, %3" : "=v"(d) : "v"(a), "v"(b), "v"(c)); return d;
}
__device__ __forceinline__ unsigned pk_mul(unsigned a, unsigned b) {
    unsigned d; asm("v_pk_mul_f16 %0, %1, %2" : "=v"(d) : "v"(a), "v"(b)); return d;
}
__device__ __forceinline__ unsigned pk_add(unsigned a, unsigned b) {
    unsigned d; asm("v_pk_add_f16 %0, %1, %2" : "=v"(d) : "v"(a), "v"(b)); return d;
}
__device__ __forceinline__ unsigned pk_max(unsigned a, unsigned b) {
    unsigned d; asm("v_pk_max_f16 %0, %1, %2" : "=v"(d) : "v"(a), "v"(b)); return d;
}
__device__ __forceinline__ unsigned pk_min(unsigned a, unsigned b) {
    unsigned d; asm("v_pk_min_f16 %0, %1, %2" : "=v"(d) : "v"(a), "v"(b)); return d;
}

struct GC { unsigned c0, c1, c2, c3, c4, clo, chi; };
__device__ __forceinline__ GC make_gc() {
    GC g;
    g.c0  = cvt_pku( 1.5957600f,   1.5957600f);
    g.c1  = cvt_pku(-1.0445624f,  -1.0445624f);
    g.c2  = cvt_pku( 0.5417632f,   0.5417632f);
    g.c3  = cvt_pku(-0.15817472f, -0.15817472f);
    g.c4  = cvt_pku( 0.018604288f, 0.018604288f);
    g.clo = cvt_pku(-1.75f, -1.75f);
    g.chi = cvt_pku( 1.75f,  1.75f);
    return g;
}

// Packed-f16 gelu * w2 accumulate, PRE-HALVED input aH = x/2. 10 VOP3P / 2 values.
__device__ __forceinline__ void gelu_w2_asm(unsigned aH, unsigned w, unsigned& pacc, const GC& gc) {
    unsigned t = pk_min(pk_max(aH, gc.clo), gc.chi);
    unsigned s = pk_mul(t, t);
    unsigned p = pk_fma(gc.c4, s, gc.c3);
    p = pk_fma(p, s, gc.c2);
    p = pk_fma(p, s, gc.c1);
    p = pk_fma(p, s, gc.c0);
    unsigned e = pk_mul(t, p);
    unsigned g = pk_fma(aH, e, aH);
    pacc = pk_fma(g, w, pacc);
}

#define WAITV(n) asm volatile("s_waitcnt vmcnt(" #n ")" ::: "memory")
#define MEMBAR() asm volatile("" ::: "memory")

// ---- Stage 1: v-MLP. Block = (b, cl, tch, dhalf); 8 waves = 8 heads share one
// LDS tile of 16 rows x 512 f32. Each wave DMA-stages TWO FULL 2KB contiguous
// row-halves (4x 1KB sequential global_load_lds) -> DRAM-friendly bursts.
// Double-buffered, raw s_barrier + per-wave counted vmcnt (no syncthreads drain).
__global__ __launch_bounds__(512) void k_stage1(
    const float* __restrict__ mem, const float* __restrict__ dim_pe,
    const float* __restrict__ W1, const float* __restrict__ b1,
    const float* __restrict__ W2, const float* __restrict__ b2,
    _Float16* __restrict__ vbuf)
{
    extern __shared__ float stage[];            // [2][16][512] = 64 KB

    const int blk   = blockIdx.x;               // ((b*16+cl)*8 + tch)*2 + dhalf
    const int dhalf = blk & 1;
    const int tch   = (blk >> 1) & 7;
    const int cl    = (blk >> 4) & 15;
    const int b     = blk >> 8;
    const int lane  = threadIdx.x & 63;
    const int wv    = threadIdx.x >> 6;         // 0..7
    const int nh    = dhalf * 8 + wv;
    const int g     = lane >> 4;
    const int fl    = lane & 15;
    const int kbase = (8 * g) & 15;
    const bool klive = (g < 2);

    const float* membase = mem + (long)b * MEMROWS_ * D_;
    _Float16* vrow = vbuf + (long)(b * CL_ + cl) * T_ * D_;
    const int t0   = tch * 31 + (tch < 2 ? tch : 2);
    const int tend = (tch < 2) ? 32 : 31;

    const GC gc = make_gc();

    // pe fragments (f16, loop-invariant B upper-K content)
    h16x8 peq[4];
#pragma unroll
    for (int ct = 0; ct < 4; ++ct) {
        const int d0 = nh * DH_ + ct * 16 + fl;
        float p0 = dim_pe[(kbase + 0) * D_ + d0];
        float p1 = dim_pe[(kbase + 1) * D_ + d0];
        float p2 = dim_pe[(kbase + 2) * D_ + d0];
        float p3 = dim_pe[(kbase + 3) * D_ + d0];
        float p4 = dim_pe[(kbase + 4) * D_ + d0];
        float p5 = dim_pe[(kbase + 5) * D_ + d0];
        float p6 = dim_pe[(kbase + 6) * D_ + d0];
        float p7 = dim_pe[(kbase + 7) * D_ + d0];
        peq[ct] = packH4(cvt_pk(p0, p1), cvt_pk(p2, p3), cvt_pk(p4, p5), cvt_pk(p6, p7));
    }

    // W1^T A-fragments PRE-HALVED; b1/2 in MFMA C; W2 packed u32.
    h16x8 bfragA[4];
    f32x4 ci[4];
    unsigned w2u[8];
#pragma unroll
    for (int cn = 0; cn < 4; ++cn) {
        h16x2 q[4];
#pragma unroll
        for (int jp = 0; jp < 4; ++jp) {
            float w0 = 0.5f * W1[(nh * CRv_ + kbase + 2 * jp + 0) * HID_ + cn * 16 + fl];
            float w1 = 0.5f * W1[(nh * CRv_ + kbase + 2 * jp + 1) * HID_ + cn * 16 + fl];
            q[jp] = cvt_pk(w0, w1);
        }
        bfragA[cn] = packH4(q[0], q[1], q[2], q[3]);
#pragma unroll
        for (int r = 0; r < 4; ++r) ci[cn][r] = 0.5f * b1[nh * HID_ + cn * 16 + 4 * g + r];
        w2u[2 * cn + 0] = cvt_pku(W2[nh * HID_ + cn * 16 + 4 * g + 0],
                                  W2[nh * HID_ + cn * 16 + 4 * g + 1]);
        w2u[2 * cn + 1] = cvt_pku(W2[nh * HID_ + cn * 16 + 4 * g + 2],
                                  W2[nh * HID_ + cn * 16 + 4 * g + 3]);
    }
    const float b2s = b2[nh];
    const unsigned b2p = cvt_pku(b2s, b2s);

    // Staging: wave wv owns rows 2wv, 2wv+1. Four 1KB sequential loads per tile:
    // (row 2wv, +0KB), (row 2wv, +1KB), (row 2wv+1, +0KB), (row 2wv+1, +1KB).
    const int r0 = 2 * wv, r1 = 2 * wv + 1;
    const float* gp0 = membase + ((size_t)(cl * CRv_ + r0) * T_ + t0) * D_ + dhalf * 512 +   0 + lane * 4;
    const float* gp1 = membase + ((size_t)(cl * CRv_ + r0) * T_ + t0) * D_ + dhalf * 512 + 256 + lane * 4;
    const float* gp2 = membase + ((size_t)(cl * CRv_ + r1) * T_ + t0) * D_ + dhalf * 512 +   0 + lane * 4;
    const float* gp3 = membase + ((size_t)(cl * CRv_ + r1) * T_ + t0) * D_ + dhalf * 512 + 256 + lane * 4;

#define ISSUE(bf) do { \
    float* lb = stage + (bf) * 8192; \
    __builtin_amdgcn_global_load_lds((const AS1 void*)gp0, (AS3 void*)(lb + r0 * 512 +   0), 16, 0, 0); \
    __builtin_amdgcn_global_load_lds((const AS1 void*)gp1, (AS3 void*)(lb + r0 * 512 + 256), 16, 0, 0); \
    __builtin_amdgcn_global_load_lds((const AS1 void*)gp2, (AS3 void*)(lb + r1 * 512 +   0), 16, 0, 0); \
    __builtin_amdgcn_global_load_lds((const AS1 void*)gp3, (AS3 void*)(lb + r1 * 512 + 256), 16, 0, 0); \
    gp0 += D_; gp1 += D_; gp2 += D_; gp3 += D_; } while (0)

    ISSUE(0);                                   // tile t0 -> buf0

    for (int tt = 0; tt < tend; ++tt) {
        if (tt + 1 < tend) {
            ISSUE((tt + 1) & 1);                // prefetch next tile
            if (tt == 0) WAITV(4); else WAITV(5);
        } else {
            WAITV(1);                           // only prior store outstanding
        }
        __builtin_amdgcn_s_barrier();           // all rows of tile tt landed
        MEMBAR();

        const float* bufp = stage + (tt & 1) * 8192;
        float prl[4];
#pragma unroll
        for (int ct = 0; ct < 4; ++ct) {
            const int col = wv * 64 + ct * 16 + fl;
            float a0 = bufp[(kbase + 0) * 512 + col];
            float a1 = bufp[(kbase + 1) * 512 + col];
            float a2 = bufp[(kbase + 2) * 512 + col];
            float a3 = bufp[(kbase + 3) * 512 + col];
            float a4 = bufp[(kbase + 4) * 512 + col];
            float a5 = bufp[(kbase + 5) * 512 + col];
            float a6 = bufp[(kbase + 6) * 512 + col];
            float a7 = bufp[(kbase + 7) * 512 + col];
            h16x8 xq = packH4(cvt_pk(a0, a1), cvt_pk(a2, a3), cvt_pk(a4, a5), cvt_pk(a6, a7));
            h16x8 af = klive ? xq : peq[ct];

            f32x4 acc[4];
#pragma unroll
            for (int cn = 0; cn < 4; ++cn)
                acc[cn] = __builtin_amdgcn_mfma_f32_16x16x32_f16(bfragA[cn], af, ci[cn], 0, 0, 0);

            unsigned pc0 = 0u, pc1 = 0u;
#pragma unroll
            for (int cn = 0; cn < 4; ++cn) {
                unsigned a01 = cvt_pku(acc[cn][0], acc[cn][1]);
                unsigned a23 = cvt_pku(acc[cn][2], acc[cn][3]);
                gelu_w2_asm(a01, w2u[2 * cn + 0], pc0, gc);
                gelu_w2_asm(a23, w2u[2 * cn + 1], pc1, gc);
            }
            h16x2 P = __builtin_bit_cast(h16x2, pk_add(pc0, pc1));
            prl[ct] = (float)P[0] + (float)P[1];
        }

        unsigned A  = cvt_pku(prl[0], prl[1]);
        unsigned Bp = cvt_pku(prl[2], prl[3]);
        A  = pk_add(A,  (unsigned)__shfl_xor((int)A, 16));
        Bp = pk_add(Bp, (unsigned)__shfl_xor((int)Bp, 16));
        A  = pk_add(A,  (unsigned)__shfl_xor((int)A, 32));
        Bp = pk_add(Bp, (unsigned)__shfl_xor((int)Bp, 32));
        A  = pk_add(A, b2p);
        Bp = pk_add(Bp, b2p);
        unsigned sel = (g < 2) ? A : Bp;
        unsigned sh  = (g & 1) ? (sel >> 16) : sel;
        vrow[(size_t)(t0 + tt) * D_ + nh * DH_ + g * 16 + fl] =
            __builtin_bit_cast(_Float16, (unsigned short)sh);

        MEMBAR();
        __builtin_amdgcn_s_barrier();           // all waves done reading this buf
        MEMBAR();
    }
#undef ISSUE
}

// ---- Stage 2: h-MLP over t = tc*16+cr (pad rows -> nonsense). Pre-halved W1/b1.
__global__ __launch_bounds__(256) void k_stage2(
    const _Float16* __restrict__ vbuf, const float* __restrict__ mem,
    const float* __restrict__ W1, const float* __restrict__ b1,
    const float* __restrict__ W2, const float* __restrict__ b2,
    float* __restrict__ hbuf)
{
    const int blk = blockIdx.x;                // ((b*CL + cl)*16 + tc)*4 + nhg
    const int nhg = blk & 3;
    const int tc  = (blk >> 2) & 15;
    const int cl  = (blk >> 6) & 15;
    const int b   = blk >> 10;
    const int lane = threadIdx.x & 63;
    const int wv   = threadIdx.x >> 6;
    const int nh   = nhg * 4 + wv;
    const int g    = lane >> 4;
    const int fl   = lane & 15;
    const int kbase = (8 * g) & 15;
    const bool klive = (g < 2);

    const _Float16* vrow = vbuf + (long)(b * CL_ + cl) * T_ * D_;
    const float* nons = mem + ((long)b * MEMROWS_ + (long)L_ * T_) * D_;

    const GC gc = make_gc();

    h16x8 bfragA[4];
    f32x4 ci[4];
    unsigned w2u[8];
#pragma unroll
    for (int cn = 0; cn < 4; ++cn) {
        h16x2 q[4];
#pragma unroll
        for (int jp = 0; jp < 4; ++jp) {
            float w0 = 0.5f * W1[(nh * CRv_ + kbase + 2 * jp + 0) * HID_ + cn * 16 + fl];
            float w1 = 0.5f * W1[(nh * CRv_ + kbase + 2 * jp + 1) * HID_ + cn * 16 + fl];
            h16x2 qq = cvt_pk(w0, w1);
            if (!klive) { qq[0] = (_Float16)0.f; qq[1] = (_Float16)0.f; }
            q[jp] = qq;
        }
        bfragA[cn] = packH4(q[0], q[1], q[2], q[3]);
#pragma unroll
        for (int r = 0; r < 4; ++r) ci[cn][r] = 0.5f * b1[nh * HID_ + cn * 16 + 4 * g + r];
        w2u[2 * cn + 0] = cvt_pku(W2[nh * HID_ + cn * 16 + 4 * g + 0],
                                  W2[nh * HID_ + cn * 16 + 4 * g + 1]);
        w2u[2 * cn + 1] = cvt_pku(W2[nh * HID_ + cn * 16 + 4 * g + 2],
                                  W2[nh * HID_ + cn * 16 + 4 * g + 3]);
    }
    const float b2s = b2[nh];

#pragma unroll 1
    for (int ct = 0; ct < 4; ++ct) {
        const int d0 = nh * DH_ + ct * 16 + fl;
        const _Float16 nv = (_Float16)nons[d0];

        h16x2 q[4];
#pragma unroll
        for (int jp = 0; jp < 4; ++jp) {
            h16x2 qq;
#pragma unroll
            for (int e = 0; e < 2; ++e) {
                const int t   = tc * CRv_ + kbase + 2 * jp + e;
                const int tcl = (t < T_) ? t : (T_ - 1);
                _Float16 us = vrow[tcl * D_ + d0];
                qq[e] = (t < T_) ? us : nv;
            }
            q[jp] = qq;
        }
        h16x8 af = packH4(q[0], q[1], q[2], q[3]);

        f32x4 acc[4];
#pragma unroll
        for (int cn = 0; cn < 4; ++cn)
            acc[cn] = __builtin_amdgcn_mfma_f32_16x16x32_f16(bfragA[cn], af, ci[cn], 0, 0, 0);

        unsigned pc0 = 0u, pc1 = 0u;
#pragma unroll
        for (int cn = 0; cn < 4; ++cn) {
            unsigned a01 = cvt_pku(acc[cn][0], acc[cn][1]);
            unsigned a23 = cvt_pku(acc[cn][2], acc[cn][3]);
            gelu_w2_asm(a01, w2u[2 * cn + 0], pc0, gc);
            gelu_w2_asm(a23, w2u[2 * cn + 1], pc1, gc);
        }
        h16x2 P = __builtin_bit_cast(h16x2, pk_add(pc0, pc1));
        float pr = (float)P[0] + (float)P[1];
        pr += __shfl_xor(pr, 16);
        pr += __shfl_xor(pr, 32);

        if (g == 0)
            hbuf[(long)((b * CL_ + cl) * 16 + tc) * D_ + d0] = pr + b2s;
    }
}

// ---- Stage 3: C(512x1024) = H @ projW^T + bias (fp32 tiled GEMM)
__global__ __launch_bounds__(256) void k_proj(
    const float* __restrict__ H, const float* __restrict__ Wp,
    const float* __restrict__ bias, float* __restrict__ Cout)
{
    constexpr int BM = 32, BN = 64, BK = 32, K = 1024, NCOLB = OUT_ / BN; // 16
    __shared__ float Ht[BM][BK + 1];
    __shared__ float Wt[BN][BK + 1];

    const int bn = blockIdx.x % NCOLB;
    const int bm = blockIdx.x / NCOLB;
    const int tid = threadIdx.x;
    const int tx = tid & 15;
    const int ty = tid >> 4;
    const int lr = tid >> 3;
    const int lc = (tid & 7) << 2;

    float acc[2][4] = {};

    for (int k0 = 0; k0 < K; k0 += BK) {
        float4 hv  = *(const float4*)(H  + (long)(bm * BM + lr) * K + k0 + lc);
        float4 w0  = *(const float4*)(Wp + (long)(bn * BN + lr) * K + k0 + lc);
        float4 w1v = *(const float4*)(Wp + (long)(bn * BN + 32 + lr) * K + k0 + lc);
        Ht[lr][lc + 0] = hv.x;  Ht[lr][lc + 1] = hv.y;  Ht[lr][lc + 2] = hv.z;  Ht[lr][lc + 3] = hv.w;
        Wt[lr][lc + 0] = w0.x;  Wt[lr][lc + 1] = w0.y;  Wt[lr][lc + 2] = w0.z;  Wt[lr][lc + 3] = w0.w;
        Wt[32 + lr][lc + 0] = w1v.x; Wt[32 + lr][lc + 1] = w1v.y; Wt[32 + lr][lc + 2] = w1v.z; Wt[32 + lr][lc + 3] = w1v.w;
        __syncthreads();

#pragma unroll
        for (int kk = 0; kk < BK; ++kk) {
            float va0 = Ht[ty * 2 + 0][kk];
            float va1 = Ht[ty * 2 + 1][kk];
            float vb0 = Wt[tx * 4 + 0][kk];
            float vb1 = Wt[tx * 4 + 1][kk];
            float vb2 = Wt[tx * 4 + 2][kk];
            float vb3 = Wt[tx * 4 + 3][kk];
            acc[0][0] = fmaf(va0, vb0, acc[0][0]);
            acc[0][1] = fmaf(va0, vb1, acc[0][1]);
            acc[0][2] = fmaf(va0, vb2, acc[0][2]);
            acc[0][3] = fmaf(va0, vb3, acc[0][3]);
            acc[1][0] = fmaf(va1, vb0, acc[1][0]);
            acc[1][1] = fmaf(va1, vb1, acc[1][1]);
            acc[1][2] = fmaf(va1, vb2, acc[1][2]);
            acc[1][3] = fmaf(va1, vb3, acc[1][3]);
        }
        __syncthreads();
    }

#pragma unroll
    for (int i = 0; i < 2; ++i) {
#pragma unroll
        for (int jj = 0; jj < 4; ++jj) {
            int r = bm * BM + ty * 2 + i;
            int c = bn * BN + tx * 4 + jj;
            Cout[(long)r * OUT_ + c] = acc[i][jj] + bias[c];
        }
    }
}

extern "C" void kernel_launch(void* const* d_in, const int* in_sizes, int n_in,
                              void* d_out, int out_size, void* d_ws, size_t ws_size,
                              hipStream_t stream) {
    const float* mem    = (const float*)d_in[0];
    const float* dim_pe = (const float*)d_in[2];
    const float* vW1    = (const float*)d_in[3];
    const float* vb1    = (const float*)d_in[4];
    const float* vW2    = (const float*)d_in[5];
    const float* vb2    = (const float*)d_in[6];
    const float* hW1    = (const float*)d_in[7];
    const float* hb1    = (const float*)d_in[8];
    const float* hW2    = (const float*)d_in[9];
    const float* hb2    = (const float*)d_in[10];
    const float* projW  = (const float*)d_in[11];
    const float* projb  = (const float*)d_in[12];
    float* out = (float*)d_out;

    _Float16* vbuf = (_Float16*)d_ws;                                   // f16, 16 MB
    float* hbuf = (float*)((char*)d_ws + (size_t)B_ * CL_ * T_ * D_ * sizeof(_Float16));

    // 512 blocks = (b, cl, tch(8), dhalf(2)); 512 threads; 64 KB dynamic LDS
    k_stage1<<<B_ * CL_ * 8 * 2, 512, 65536, stream>>>(mem, dim_pe, vW1, vb1, vW2, vb2, vbuf);
    k_stage2<<<B_ * CL_ * 16 * 4, 256, 0, stream>>>(vbuf, mem, hW1, hb1, hW2, hb2, hbuf);
    k_proj<<<(512 / 32) * (OUT_ / 64), 256, 0, stream>>>(hbuf, projW, projb, out);
}